// Round 8
// baseline (81.238 us; speedup 1.0000x reference)
//
#include <hip/hip_runtime.h>
#include <math.h>

constexpr int NQ  = 12;
constexpr int NS  = 1 << NQ;   // 4096 amplitudes
constexpr int NL  = 4;
constexpr int BLK = 256;
constexpr int R   = 16;        // amplitudes per thread (reg bits = amp bits 0..3)
constexpr float PI_F = 3.14159265358979323846f;

// ws layout (floats): [0..3] entangler bitmask (uint64) | [4..387] gmat 48x4 c32
//                     [512 ...] uenc 256 samples x 12 qubits x 2 c32
constexpr int WS_GMAT_F = 4;
constexpr int WS_UENC_F = 512;

// amp index i = (tid << 4) | r
//   bits 0..3  : register index r
//   bits 4..9  : lane bits (tid bits 0..5)
//   bits 10..11: wave bits (tid bits 6..7)

typedef float c32 __attribute__((ext_vector_type(2)));   // (re, im)

__device__ __forceinline__ c32 cmul(c32 a, c32 b) {
    c32 t = (c32){-a.y, a.y} * b.yx;
    return (c32){a.x, a.x} * b + t;
}
struct cg { c32 xx, ny; };
__device__ __forceinline__ cg mkg(c32 u) {
    cg g; g.xx = (c32){u.x, u.x}; g.ny = (c32){-u.y, u.y}; return g;
}
__device__ __forceinline__ c32 cmulg(cg g, c32 b) { return g.xx * b + g.ny * b.yx; }
__device__ __forceinline__ c32 cmadg(cg g, c32 b, c32 c) { return g.xx * b + (g.ny * b.yx + c); }

// ---------------- VALU lane-exchange primitives ----------------
// row_shr:N = lane i <- i-N, row_shl:N = lane i <- i+N (verified R5).
template<int CTRL>
__device__ __forceinline__ float dppmov(float v) {
    return __int_as_float(__builtin_amdgcn_mov_dpp(__float_as_int(v), CTRL, 0xF, 0xF, false));
}
__device__ __forceinline__ float dppx4(float v) {
    int s = __float_as_int(v);
    int o = __builtin_amdgcn_update_dpp(s, s, 0x104, 0xF, 0x5, false); // row_shl:4 -> banks 0,2
    o     = __builtin_amdgcn_update_dpp(o, s, 0x114, 0xF, 0xA, false); // row_shr:4 -> banks 1,3
    return __int_as_float(o);
}

#if __has_builtin(__builtin_amdgcn_permlane16_swap)
#define HAVE_PL16 1
#endif
#if __has_builtin(__builtin_amdgcn_permlane32_swap)
#define HAVE_PL32 1
#endif

template<int M>
__device__ __forceinline__ float lanex(float v, int tid) {
    if constexpr (M == 1)  return dppmov<0xB1>(v);        // quad_perm [1,0,3,2]
    else if constexpr (M == 2)  return dppmov<0x4E>(v);   // quad_perm [2,3,0,1]
    else if constexpr (M == 4)  return dppx4(v);
    else if constexpr (M == 8)  return dppmov<0x128>(v);  // row_ror:8
    else if constexpr (M == 16) {
#ifdef HAVE_PL16
        auto r = __builtin_amdgcn_permlane16_swap(__float_as_int(v), __float_as_int(v), false, false);
        return __int_as_float((tid & 16) ? r[0] : r[1]);
#else
        return __shfl_xor(v, 16, 64);
#endif
    } else { // M == 32
#ifdef HAVE_PL32
        auto r = __builtin_amdgcn_permlane32_swap(__float_as_int(v), __float_as_int(v), false, false);
        return __int_as_float((tid & 32) ? r[0] : r[1]);
#else
        return __shfl_xor(v, 32, 64);
#endif
    }
}
template<int M>
__device__ __forceinline__ c32 cx(c32 v, int tid) {
    return (c32){lanex<M>(v.x, tid), lanex<M>(v.y, tid)};
}

template<int P>
__device__ __forceinline__ void gate_reg(c32* v, const c32* u) {
    const cg g00 = mkg(u[0]), g01 = mkg(u[1]), g10 = mkg(u[2]), g11 = mkg(u[3]);
    #pragma unroll
    for (int r = 0; r < R; ++r)
        if (!(r & (1 << P))) {
            c32 a = v[r], b = v[r | (1 << P)];
            v[r]            = cmadg(g01, b, cmulg(g00, a));
            v[r | (1 << P)] = cmadg(g11, b, cmulg(g10, a));
        }
}

template<int M>
__device__ __forceinline__ void gate_lane(c32* v, int tid, const c32* u) {
    const bool hi = tid & M;
    const c32 Ud = hi ? u[3] : u[0];
    const c32 Uo = hi ? u[2] : u[1];
    const cg gd = mkg(Ud), go = mkg(Uo);
    #pragma unroll
    for (int r = 0; r < R; ++r) {
        c32 o = cx<M>(v[r], tid);
        v[r] = cmadg(gd, v[r], cmulg(go, o));
    }
}

template<int CM, int TM>
__device__ __forceinline__ void cnot_ll(c32* v, int tid) {
    const bool c_ = tid & CM;
    #pragma unroll
    for (int r = 0; r < R; ++r) {
        c32 o = cx<TM>(v[r], tid);
        if (c_) v[r] = o;
    }
}

template<int PC, int PT>
__device__ __forceinline__ void cnot_rr(c32* v) {
    #pragma unroll
    for (int r = 0; r < R; ++r)
        if ((r & (1 << PC)) && !(r & (1 << PT))) {
            c32 t = v[r]; v[r] = v[r ^ (1 << PT)]; v[r ^ (1 << PT)] = t;
        }
}

// ================= prep kernel: all block-uniform precompute -> global ws ====
__global__ __launch_bounds__(64, 1)
void prep_kernel(const float* __restrict__ x, const float* __restrict__ w,
                 const float* __restrict__ ent, float* __restrict__ ws)
{
    const int b   = blockIdx.x;
    const int tid = threadIdx.x;

    // per-sample encoding 2-vectors
    if (tid < NQ) {
        float xv = x[b * NQ + tid];
        float s, c;   sincosf(0.5f * PI_F * xv, &s, &c);
        float zs, zc; sincosf(0.5f * PI_F * xv * xv, &zs, &zc);
        c32* ue = (c32*)(ws + WS_UENC_F) + b * (NQ * 2);
        ue[2 * tid + 0] = (c32){c * zc, -c * zs};
        ue[2 * tid + 1] = (c32){s * zc,  s * zs};
    }
    if (b == 0) {
        bool f = false;
        if (tid < NL * NQ) {
            float phi = w[tid * 3 + 0], th = w[tid * 3 + 1], om = w[tid * 3 + 2];
            float s, c;   sincosf(0.5f * th, &s, &c);
            float sa, ca; sincosf(0.5f * (phi + om), &sa, &ca);
            float sm, cm; sincosf(0.5f * (phi - om), &sm, &cm);
            c32* gm = (c32*)(ws + WS_GMAT_F) + tid * 4;
            gm[0] = (c32){ c * ca, -c * sa};
            gm[1] = (c32){-s * cm, -s * sm};
            gm[2] = (c32){ s * cm, -s * sm};
            gm[3] = (c32){ c * ca,  c * sa};
            f = ent[tid] > 0.5f;
        }
        unsigned long long m = __ballot(f);
        if (tid == 0) *((unsigned long long*)ws) = m;
    }
}

// ================= main kernel ===============================================
__global__ __launch_bounds__(BLK, 1)
void qsim_kernel(const float* __restrict__ ws, float* __restrict__ out)
{
    __shared__ c32  xbuf[NS];           // 32 KB cross-wave exchange
    __shared__ float redbuf[4 * NQ];

    const int tid = threadIdx.x;
    const int b   = blockIdx.x;

    const unsigned long long em = *((const unsigned long long*)ws);  // uniform -> SGPR
    const c32* gmat = (const c32*)(ws + WS_GMAT_F);
    const c32* ue   = (const c32*)(ws + WS_UENC_F) + b * (NQ * 2);

    // ---- encoded product state in registers ----
    c32 A = ue[2 * 0 + ((tid >> 7) & 1)];
    #pragma unroll
    for (int q = 1; q < 8; ++q) A = cmul(A, ue[2 * q + ((tid >> (7 - q)) & 1)]);
    c32 AP[4], PAB[4];
    #pragma unroll
    for (int j = 0; j < 4; ++j)
        AP[j] = cmul(A, cmul(ue[16 + (j >> 1)], ue[18 + (j & 1)]));
    #pragma unroll
    for (int k = 0; k < 4; ++k)
        PAB[k] = cmul(ue[20 + (k >> 1)], ue[22 + (k & 1)]);
    c32 v[R];
    #pragma unroll
    for (int r = 0; r < R; ++r) v[r] = cmul(AP[(r >> 2) & 3], PAB[r & 3]);

    const int lane_slot = tid & 63;
    const int g         = tid >> 6;   // quadrant = amp bits (11,10)

    // ---- layers ----
    #pragma unroll 1
    for (int layer = 0; layer < NL; ++layer) {
        const int gb = layer * NQ;
        const c32* gm = gmat + gb * 4;   // this layer's 12 gates x 4 coeffs

        // ===== fused 4x4 gate on amp bits (11,10) =====
        {
            const int  gp = (((em >> (gb + 0)) & 1) && (g & 2)) ? (g ^ 1) : g;
            const int  ar = (gp >> 1) * 2, br = (gp & 1) * 2;
            c32 rowE[4];
            rowE[0] = cmul(gm[ar + 0], gm[4 + br + 0]);
            rowE[1] = cmul(gm[ar + 0], gm[4 + br + 1]);
            rowE[2] = cmul(gm[ar + 1], gm[4 + br + 0]);
            rowE[3] = cmul(gm[ar + 1], gm[4 + br + 1]);
            const bool pf = (layer > 0) && ((em >> (gb - 1)) & 1);   // prev CNOT(0,11)
            cg gE[4], gO[4];
            #pragma unroll
            for (int j = 0; j < 4; ++j) {
                gE[j] = mkg(rowE[j]);
                gO[j] = mkg(pf ? rowE[j ^ 2] : rowE[j]);
            }

            #pragma unroll
            for (int r = 0; r < R; ++r) xbuf[r * BLK + tid] = v[r];
            __syncthreads();
            #pragma unroll
            for (int r = 0; r < R; ++r) {
                const cg* rw = (r & 1) ? gO : gE;
                c32 acc = cmulg(rw[0], xbuf[r * BLK +   0 + lane_slot]);
                acc     = cmadg(rw[1], xbuf[r * BLK +  64 + lane_slot], acc);
                acc     = cmadg(rw[2], xbuf[r * BLK + 128 + lane_slot], acc);
                acc     = cmadg(rw[3], xbuf[r * BLK + 192 + lane_slot], acc);
                v[r] = acc;
            }
            __syncthreads();
        }

        // ===== Rot gates on lane bits and reg bits =====
        gate_lane<32>(v, tid, gm + 2  * 4);
        gate_lane<16>(v, tid, gm + 3  * 4);
        gate_lane< 8>(v, tid, gm + 4  * 4);
        gate_lane< 4>(v, tid, gm + 5  * 4);
        gate_lane< 2>(v, tid, gm + 6  * 4);
        gate_lane< 1>(v, tid, gm + 7  * 4);
        gate_reg<3>(v, gm + 8  * 4);
        gate_reg<2>(v, gm + 9  * 4);
        gate_reg<1>(v, gm + 10 * 4);
        gate_reg<0>(v, gm + 11 * 4);

        // ===== CNOT chain (q=0 folded above; q=11 folded forward) =====
        if (((em >> (gb + 1)) & 1) && (tid & 64)) {  // (10,9)
            #pragma unroll
            for (int r = 0; r < R; ++r) v[r] = cx<32>(v[r], tid);
        }
        if ((em >> (gb + 2)) & 1) cnot_ll<32, 16>(v, tid);   // (9,8)
        if ((em >> (gb + 3)) & 1) cnot_ll<16,  8>(v, tid);   // (8,7)
        if ((em >> (gb + 4)) & 1) cnot_ll< 8,  4>(v, tid);   // (7,6)
        if ((em >> (gb + 5)) & 1) cnot_ll< 4,  2>(v, tid);   // (6,5)
        if ((em >> (gb + 6)) & 1) cnot_ll< 2,  1>(v, tid);   // (5,4)
        if ((em >> (gb + 7)) & 1) {                          // (4,3)
            const bool c_ = tid & 1;
            #pragma unroll
            for (int r = 0; r < 8; ++r) {
                c32 a = v[r], bb = v[r | 8];
                v[r]     = c_ ? bb : a;
                v[r | 8] = c_ ? a  : bb;
            }
        }
        if ((em >> (gb + 8)) & 1)  cnot_rr<3, 2>(v);         // (3,2)
        if ((em >> (gb + 9)) & 1)  cnot_rr<2, 1>(v);         // (2,1)
        if ((em >> (gb + 10)) & 1) cnot_rr<1, 0>(v);         // (1,0)
        // q=11 CNOT(0,11): folded into next fused gate, or into measurement
    }

    // ---- measurement; last layer's CNOT(0,11) folded into q0's sign ----
    const bool e011L = (em >> ((NL - 1) * NQ + 11)) & 1;
    const int  t7    = (tid >> 7) & 1;

    float pr[R];
    #pragma unroll
    for (int r = 0; r < R; ++r) {
        c32 p = v[r] * v[r];
        pr[r] = p.x + p.y;
    }
    float S = 0.f, acc0 = 0.f;
    #pragma unroll
    for (int r = 0; r < R; ++r) {
        S += pr[r];
        const int s11 = t7 ^ (e011L & (r & 1));
        acc0 += s11 ? -pr[r] : pr[r];
    }
    float T[4];
    #pragma unroll
    for (int pb = 0; pb < 4; ++pb) {
        float t = 0.f;
        #pragma unroll
        for (int r = 0; r < R; ++r) t += ((r >> pb) & 1) ? -pr[r] : pr[r];
        T[pb] = t;
    }

    float contrib[NQ];
    contrib[0] = acc0;
    #pragma unroll
    for (int q = 1; q < 8; ++q) contrib[q] = ((tid >> (7 - q)) & 1) ? -S : S;
    contrib[8] = T[3]; contrib[9] = T[2]; contrib[10] = T[1]; contrib[11] = T[0];

    #pragma unroll
    for (int off = 32; off; off >>= 1) {
        #pragma unroll
        for (int q = 0; q < NQ; ++q) contrib[q] += __shfl_xor(contrib[q], off, 64);
    }
    if ((tid & 63) == 0) {
        const int wv = tid >> 6;
        #pragma unroll
        for (int q = 0; q < NQ; ++q) redbuf[wv * NQ + q] = contrib[q];
    }
    __syncthreads();
    if (tid < NQ)
        out[b * NQ + tid] = redbuf[tid] + redbuf[NQ + tid] + redbuf[2 * NQ + tid] + redbuf[3 * NQ + tid];
}

extern "C" void kernel_launch(void* const* d_in, const int* in_sizes, int n_in,
                              void* d_out, int out_size, void* d_ws, size_t ws_size,
                              hipStream_t stream) {
    const float* x   = (const float*)d_in[0];  // (B,12)
    const float* w   = (const float*)d_in[1];  // (4,12,3)
    const float* ent = (const float*)d_in[2];  // (4,12)
    float* out = (float*)d_out;
    float* ws  = (float*)d_ws;
    const int B = in_sizes[0] / NQ;
    prep_kernel<<<B, 64, 0, stream>>>(x, w, ent, ws);
    qsim_kernel<<<B, BLK, 0, stream>>>(ws, out);
}

// Round 9
// 79.402 us; speedup vs baseline: 1.0231x; 1.0231x over previous
//
#include <hip/hip_runtime.h>
#include <math.h>

constexpr int NQ  = 12;
constexpr int NS  = 1 << NQ;   // 4096 amplitudes
constexpr int NL  = 4;
constexpr int BLK = 256;
constexpr int R   = 16;        // amplitudes per thread (reg bits = amp bits 0..3)
constexpr float PI_F = 3.14159265358979323846f;

// amp index i = (tid << 4) | r
//   bits 0..3  : register index r
//   bits 4..9  : lane bits (tid bits 0..5)
//   bits 10..11: wave bits (tid bits 6..7)

typedef float c32 __attribute__((ext_vector_type(2)));   // (re, im) -> v_pk_* math

__device__ __forceinline__ c32 cmul(c32 a, c32 b) {
    c32 t = (c32){-a.y, a.y} * b.yx;
    return (c32){a.x, a.x} * b + t;
}
struct cg { c32 xx, ny; };
__device__ __forceinline__ cg mkg(c32 u) {
    cg g; g.xx = (c32){u.x, u.x}; g.ny = (c32){-u.y, u.y}; return g;
}
__device__ __forceinline__ c32 cmulg(cg g, c32 b) { return g.xx * b + g.ny * b.yx; }
__device__ __forceinline__ c32 cmadg(cg g, c32 b, c32 c) { return g.xx * b + (g.ny * b.yx + c); }

// ---------------- VALU lane-exchange primitives ----------------
// row_shr:N = lane i <- i-N, row_shl:N = lane i <- i+N (verified R5).
template<int CTRL>
__device__ __forceinline__ float dppmov(float v) {
    return __int_as_float(__builtin_amdgcn_mov_dpp(__float_as_int(v), CTRL, 0xF, 0xF, false));
}
__device__ __forceinline__ float dppx4(float v) {
    int s = __float_as_int(v);
    int o = __builtin_amdgcn_update_dpp(s, s, 0x104, 0xF, 0x5, false); // row_shl:4 -> banks 0,2
    o     = __builtin_amdgcn_update_dpp(o, s, 0x114, 0xF, 0xA, false); // row_shr:4 -> banks 1,3
    return __int_as_float(o);
}

#if __has_builtin(__builtin_amdgcn_permlane16_swap)
#define HAVE_PL16 1
#endif
#if __has_builtin(__builtin_amdgcn_permlane32_swap)
#define HAVE_PL32 1
#endif

template<int M>
__device__ __forceinline__ float lanex(float v, int tid) {
    if constexpr (M == 1)  return dppmov<0xB1>(v);        // quad_perm [1,0,3,2]
    else if constexpr (M == 2)  return dppmov<0x4E>(v);   // quad_perm [2,3,0,1]
    else if constexpr (M == 4)  return dppx4(v);
    else if constexpr (M == 8)  return dppmov<0x128>(v);  // row_ror:8
    else if constexpr (M == 16) {
#ifdef HAVE_PL16
        auto r = __builtin_amdgcn_permlane16_swap(__float_as_int(v), __float_as_int(v), false, false);
        return __int_as_float((tid & 16) ? r[0] : r[1]);
#else
        return __shfl_xor(v, 16, 64);
#endif
    } else { // M == 32
#ifdef HAVE_PL32
        auto r = __builtin_amdgcn_permlane32_swap(__float_as_int(v), __float_as_int(v), false, false);
        return __int_as_float((tid & 32) ? r[0] : r[1]);
#else
        return __shfl_xor(v, 32, 64);
#endif
    }
}
template<int M>
__device__ __forceinline__ c32 cx(c32 v, int tid) {
    return (c32){lanex<M>(v.x, tid), lanex<M>(v.y, tid)};
}

template<int P>
__device__ __forceinline__ void gate_reg(c32* v, const c32* u) {
    const cg g00 = mkg(u[0]), g01 = mkg(u[1]), g10 = mkg(u[2]), g11 = mkg(u[3]);
    #pragma unroll
    for (int r = 0; r < R; ++r)
        if (!(r & (1 << P))) {
            c32 a = v[r], b = v[r | (1 << P)];
            v[r]            = cmadg(g01, b, cmulg(g00, a));
            v[r | (1 << P)] = cmadg(g11, b, cmulg(g10, a));
        }
}

template<int M>
__device__ __forceinline__ void gate_lane(c32* v, int tid, const c32* u) {
    const bool hi = tid & M;
    const c32 Ud = hi ? u[3] : u[0];
    const c32 Uo = hi ? u[2] : u[1];
    const cg gd = mkg(Ud), go = mkg(Uo);
    #pragma unroll
    for (int r = 0; r < R; ++r) {
        c32 o = cx<M>(v[r], tid);
        v[r] = cmadg(gd, v[r], cmulg(go, o));
    }
}

// exec-masked CNOT: DPP reads source-lane VGPRs regardless of EXEC, and the
// partner lane (differs only in target bit) shares the control bit, so the
// masked form is safe and halves the per-amp op count vs cndmask.
template<int CM, int TM>
__device__ __forceinline__ void cnot_ll(c32* v, int tid) {
    if (tid & CM) {
        #pragma unroll
        for (int r = 0; r < R; ++r) v[r] = cx<TM>(v[r], tid);
    }
}

template<int PC, int PT>
__device__ __forceinline__ void cnot_rr(c32* v) {
    #pragma unroll
    for (int r = 0; r < R; ++r)
        if ((r & (1 << PC)) && !(r & (1 << PT))) {
            c32 t = v[r]; v[r] = v[r ^ (1 << PT)]; v[r ^ (1 << PT)] = t;
        }
}

__global__ __launch_bounds__(BLK, 1)
void qsim_kernel(const float* __restrict__ x,    // (B,12)
                 const float* __restrict__ w,    // (4,12,3)
                 const float* __restrict__ ent,  // (4,12)
                 float* __restrict__ out)        // (B,12)
{
    __shared__ c32  xbuf[NS];           // 32 KB cross-wave exchange
    __shared__ c32  gmat[NL * NQ][4];
    __shared__ c32  uenc[NQ][2];
    __shared__ int  entf[NL * NQ];
    __shared__ float redbuf[4 * NQ];

    const int tid = threadIdx.x;
    const int b   = blockIdx.x;

    if (tid < NL * NQ) {
        float phi = w[tid * 3 + 0], th = w[tid * 3 + 1], om = w[tid * 3 + 2];
        float s, c;   sincosf(0.5f * th, &s, &c);
        float sa, ca; sincosf(0.5f * (phi + om), &sa, &ca);
        float sm, cm; sincosf(0.5f * (phi - om), &sm, &cm);
        gmat[tid][0] = (c32){ c * ca, -c * sa};
        gmat[tid][1] = (c32){-s * cm, -s * sm};
        gmat[tid][2] = (c32){ s * cm, -s * sm};
        gmat[tid][3] = (c32){ c * ca,  c * sa};
        entf[tid] = ent[tid] > 0.5f;
    }
    if (tid >= 64 && tid < 64 + NQ) {
        int q = tid - 64;
        float xv = x[b * NQ + q];
        float s, c;   sincosf(0.5f * PI_F * xv, &s, &c);
        float zs, zc; sincosf(0.5f * PI_F * xv * xv, &zs, &zc);
        uenc[q][0] = (c32){c * zc, -c * zs};
        uenc[q][1] = (c32){s * zc,  s * zs};
    }
    __syncthreads();

    // ---- build encoded product state directly in registers ----
    c32 A = uenc[0][(tid >> 7) & 1];
    #pragma unroll
    for (int q = 1; q < 8; ++q) A = cmul(A, uenc[q][(tid >> (7 - q)) & 1]);
    c32 AP[4], PAB[4];
    #pragma unroll
    for (int j = 0; j < 4; ++j)
        AP[j] = cmul(A, cmul(uenc[8][j >> 1], uenc[9][j & 1]));
    #pragma unroll
    for (int k = 0; k < 4; ++k)
        PAB[k] = cmul(uenc[10][k >> 1], uenc[11][k & 1]);
    c32 v[R];
    #pragma unroll
    for (int r = 0; r < R; ++r) v[r] = cmul(AP[(r >> 2) & 3], PAB[r & 3]);

    const int lane_slot = tid & 63;
    const int g         = tid >> 6;   // quadrant = amp bits (11,10)

    // ---- layers ----
    #pragma unroll 1
    for (int layer = 0; layer < NL; ++layer) {
        const int gb = layer * NQ;

        // ===== fused 4x4 gate on amp bits (11,10) =====
        //   = Rot(bit11) ⊗ Rot(bit10), + this layer's CNOT(11,10) as row perm
        //   + prev layer's CNOT(0,11) as column perm on odd-r amplitudes.
        {
            // store state FIRST so ds_write latency overlaps coefficient setup
            #pragma unroll
            for (int r = 0; r < R; ++r) xbuf[r * BLK + tid] = v[r];

            const c32* Ua = gmat[gb + 0];
            const c32* Ub = gmat[gb + 1];
            const int  gp = (entf[gb + 0] && (g & 2)) ? (g ^ 1) : g;  // CNOT(11,10) fold
            const int  ar = (gp >> 1) * 2, br = (gp & 1) * 2;
            c32 rowE[4];
            rowE[0] = cmul(Ua[ar + 0], Ub[br + 0]);
            rowE[1] = cmul(Ua[ar + 0], Ub[br + 1]);
            rowE[2] = cmul(Ua[ar + 1], Ub[br + 0]);
            rowE[3] = cmul(Ua[ar + 1], Ub[br + 1]);
            const bool pf = (layer > 0) && entf[gb - 1];              // prev CNOT(0,11) fold
            cg gE[4], gO[4];
            #pragma unroll
            for (int j = 0; j < 4; ++j) {
                gE[j] = mkg(rowE[j]);
                gO[j] = mkg(pf ? rowE[j ^ 2] : rowE[j]);
            }

            __syncthreads();
            #pragma unroll
            for (int r = 0; r < R; ++r) {
                const cg* rw = (r & 1) ? gO : gE;
                c32 acc = cmulg(rw[0], xbuf[r * BLK +   0 + lane_slot]);
                acc     = cmadg(rw[1], xbuf[r * BLK +  64 + lane_slot], acc);
                acc     = cmadg(rw[2], xbuf[r * BLK + 128 + lane_slot], acc);
                acc     = cmadg(rw[3], xbuf[r * BLK + 192 + lane_slot], acc);
                v[r] = acc;
            }
            __syncthreads();
        }

        // ===== Rot gates on lane bits and reg bits =====
        gate_lane<32>(v, tid, gmat[gb + 2]);
        gate_lane<16>(v, tid, gmat[gb + 3]);
        gate_lane< 8>(v, tid, gmat[gb + 4]);
        gate_lane< 4>(v, tid, gmat[gb + 5]);
        gate_lane< 2>(v, tid, gmat[gb + 6]);
        gate_lane< 1>(v, tid, gmat[gb + 7]);
        gate_reg<3>(v, gmat[gb + 8]);
        gate_reg<2>(v, gmat[gb + 9]);
        gate_reg<1>(v, gmat[gb + 10]);
        gate_reg<0>(v, gmat[gb + 11]);

        // ===== CNOT chain (q=0 folded above; q=11 folded forward) =====
        if (entf[gb + 1] && (tid & 64)) {      // (10,9): ctrl wave bit6, tgt lane bit5
            #pragma unroll
            for (int r = 0; r < R; ++r) v[r] = cx<32>(v[r], tid);
        }
        if (entf[gb + 2]) cnot_ll<32, 16>(v, tid);   // (9,8)
        if (entf[gb + 3]) cnot_ll<16,  8>(v, tid);   // (8,7)
        if (entf[gb + 4]) cnot_ll< 8,  4>(v, tid);   // (7,6)
        if (entf[gb + 5]) cnot_ll< 4,  2>(v, tid);   // (6,5)
        if (entf[gb + 6]) cnot_ll< 2,  1>(v, tid);   // (5,4)
        if (entf[gb + 7]) {                          // (4,3): ctrl lane bit0, tgt reg bit3
            const bool c_ = tid & 1;
            #pragma unroll
            for (int r = 0; r < 8; ++r) {
                c32 a = v[r], bb = v[r | 8];
                v[r]     = c_ ? bb : a;
                v[r | 8] = c_ ? a  : bb;
            }
        }
        if (entf[gb + 8])  cnot_rr<3, 2>(v);         // (3,2)
        if (entf[gb + 9])  cnot_rr<2, 1>(v);         // (2,1)
        if (entf[gb + 10]) cnot_rr<1, 0>(v);         // (1,0)
        // q=11 CNOT(0,11): folded into next fused gate, or into measurement
    }

    // ---- measurement; last layer's CNOT(0,11) folded into q0's sign ----
    const bool e011L = entf[(NL - 1) * NQ + 11];
    const int  t7    = (tid >> 7) & 1;

    float pr[R];
    #pragma unroll
    for (int r = 0; r < R; ++r) {
        c32 p = v[r] * v[r];
        pr[r] = p.x + p.y;
    }
    float S = 0.f, acc0 = 0.f;
    #pragma unroll
    for (int r = 0; r < R; ++r) {
        S += pr[r];
        const int s11 = t7 ^ (e011L & (r & 1));
        acc0 += s11 ? -pr[r] : pr[r];
    }
    float T[4];
    #pragma unroll
    for (int pb = 0; pb < 4; ++pb) {
        float t = 0.f;
        #pragma unroll
        for (int r = 0; r < R; ++r) t += ((r >> pb) & 1) ? -pr[r] : pr[r];
        T[pb] = t;
    }

    float contrib[NQ];
    contrib[0] = acc0;
    #pragma unroll
    for (int q = 1; q < 8; ++q) contrib[q] = ((tid >> (7 - q)) & 1) ? -S : S;
    contrib[8] = T[3]; contrib[9] = T[2]; contrib[10] = T[1]; contrib[11] = T[0];

    // all-VALU wave reduction (DPP/permlane instead of ds_bpermute shuffles)
    #pragma unroll
    for (int q = 0; q < NQ; ++q) {
        contrib[q] += lanex< 1>(contrib[q], tid);
        contrib[q] += lanex< 2>(contrib[q], tid);
        contrib[q] += lanex< 4>(contrib[q], tid);
        contrib[q] += lanex< 8>(contrib[q], tid);
        contrib[q] += lanex<16>(contrib[q], tid);
        contrib[q] += lanex<32>(contrib[q], tid);
    }
    if ((tid & 63) == 0) {
        const int wv = tid >> 6;
        #pragma unroll
        for (int q = 0; q < NQ; ++q) redbuf[wv * NQ + q] = contrib[q];
    }
    __syncthreads();
    if (tid < NQ)
        out[b * NQ + tid] = redbuf[tid] + redbuf[NQ + tid] + redbuf[2 * NQ + tid] + redbuf[3 * NQ + tid];
}

extern "C" void kernel_launch(void* const* d_in, const int* in_sizes, int n_in,
                              void* d_out, int out_size, void* d_ws, size_t ws_size,
                              hipStream_t stream) {
    const float* x   = (const float*)d_in[0];  // (B,12)
    const float* w   = (const float*)d_in[1];  // (4,12,3)
    const float* ent = (const float*)d_in[2];  // (4,12)
    float* out = (float*)d_out;
    const int B = in_sizes[0] / NQ;
    qsim_kernel<<<B, BLK, 0, stream>>>(x, w, ent, out);
}